// Round 6
// baseline (217.842 us; speedup 1.0000x reference)
//
#include <hip/hip_runtime.h>

// Reference: B=16, L=4096, D=512, HORIZON=100
// out[b,l,d] = tokens[b,l,d] + sin(l * (freq[d] + phase[d]))   if l <  len[b]
//            = cls[d]                                          if l == len[b]
//            = 0                                               otherwise
// freq = 100^{-(d - d%2)/512}, phase = (pi/2)*(d%2); phase is added to the
// COEFFICIENT (inside the product with l), replicated exactly.
//
// R3: nontemporal stores -> 2.34x write amplification; use cached stores.
// R5->R6: one ROW per thread (half-wave t>>5 owns row, thread covers
// d4 = (t&31)+32k). All 4 token loads sit under ONE branch -> compiler can
// issue them back-to-back (MLP=4/thread) instead of 4 serialized
// load->sin->store round trips in divergent bodies. Wave stores stay
// contiguous (two 512B runs per instruction).
constexpr int Bc = 16;
constexpr int Lc = 4096;
constexpr int Dc = 512;
constexpr int ROWSPB = Lc + 1;                 // 4097 rows per batch
constexpr int ROWS = Bc * ROWSPB;              // 65552  (divisible by 8)
constexpr int F4_PER_ROW = Dc / 4;             // 128 float4 per row
constexpr int NBLK = ROWS / 8;                 // 8194 blocks, 8 rows each
static_assert(ROWS % 8 == 0, "rows divide evenly into blocks");

typedef float vf4 __attribute__((ext_vector_type(4)));

__global__ __launch_bounds__(256) void pe_kernel(
    const float* __restrict__ tokens,
    const int*   __restrict__ lengths,
    const float* __restrict__ cls,
    float*       __restrict__ out)
{
    const int t      = threadIdx.x;
    const int lane32 = t & 31;                       // d4 base within row
    const int row    = blockIdx.x * 8 + (t >> 5);    // one row per half-wave
    const int b      = row / ROWSPB;                 // magic-mul div
    const int l      = row - b * ROWSPB;
    const int len    = lengths[b];                   // uniform per half-wave

    const vf4* tok4 = reinterpret_cast<const vf4*>(tokens);
    const vf4* cls4 = reinterpret_cast<const vf4*>(cls);
    vf4*       out4 = reinterpret_cast<vf4*>(out);

    const size_t obase = ((size_t)row << 7) + lane32;   // out float4 index, k stride 32

    if (l < len) {
        // 4 independent 16B loads, all issued under one branch -> MLP=4
        const size_t tbase = ((size_t)(b * Lc + l) << 7) + lane32;
        vf4 tok[4];
        #pragma unroll
        for (int k = 0; k < 4; ++k)
            tok[k] = tok4[tbase + 32 * k];

        // coefficient in revolutions: even d: 100^{-d/512}/(2pi); odd: +0.25
        const float K      = 6.6438561897747395f / 512.0f;  // log2(100)/512
        const float INV2PI = 0.15915493667125702f;
        const float R2     = 0.98217170f;                   // 100^(-1/256)  (d += 2)
        const float R128   = 0.31622776601f;                // 100^(-1/4)    (d += 128)

        const int   d0b = lane32 << 2;                      // starting d for k=0
        float fe = __builtin_exp2f(-(float)d0b * K) * INV2PI;
        const float lf = (float)l;

        #pragma unroll
        for (int k = 0; k < 4; ++k) {
            float f2 = fe * R2;
            float a0 = __builtin_amdgcn_fractf(lf * fe);
            float a1 = __builtin_amdgcn_fractf(lf * (fe + 0.25f));
            float a2 = __builtin_amdgcn_fractf(lf * f2);
            float a3 = __builtin_amdgcn_fractf(lf * (f2 + 0.25f));

            vf4 r;
            r.x = tok[k].x + __builtin_amdgcn_sinf(a0);   // v_sin takes revolutions
            r.y = tok[k].y + __builtin_amdgcn_sinf(a1);
            r.z = tok[k].z + __builtin_amdgcn_sinf(a2);
            r.w = tok[k].w + __builtin_amdgcn_sinf(a3);
            out4[obase + 32 * k] = r;

            fe *= R128;                                   // advance d by 128
        }
    } else if (l == len) {
        #pragma unroll
        for (int k = 0; k < 4; ++k)
            out4[obase + 32 * k] = cls4[lane32 + 32 * k];
    } else {
        const vf4 z = (vf4){0.f, 0.f, 0.f, 0.f};
        #pragma unroll
        for (int k = 0; k < 4; ++k)
            out4[obase + 32 * k] = z;
    }
}

extern "C" void kernel_launch(void* const* d_in, const int* in_sizes, int n_in,
                              void* d_out, int out_size, void* d_ws, size_t ws_size,
                              hipStream_t stream) {
    const float* tokens  = (const float*)d_in[0];
    const int*   lengths = (const int*)d_in[1];
    const float* cls     = (const float*)d_in[2];
    float*       out     = (float*)d_out;

    pe_kernel<<<NBLK, 256, 0, stream>>>(tokens, lengths, cls, out);
}